// Round 11
// baseline (7557.339 us; speedup 1.0000x reference)
//
#include <hip/hip_runtime.h>
#include <math.h>

typedef _Float16 f16;
typedef __attribute__((__ext_vector_type__(8))) _Float16 f16x8;
typedef __attribute__((__ext_vector_type__(4))) float f32x4;
typedef __attribute__((__ext_vector_type__(2))) float fv2;

static __device__ __forceinline__ f32x4 mfma16(f16x8 a, f16x8 b, f32x4 c) {
  return __builtin_amdgcn_mfma_f32_16x16x32_f16(a, b, c, 0, 0, 0);
}
static __device__ __forceinline__ float sigf(float x) { return 1.0f / (1.0f + expf(-x)); }
static __device__ __forceinline__ void split2(float v, f16* hi, f16* lo) {
  f16 h = (f16)v;
  *hi = h;
  *lo = (f16)((v - (float)h) * 2048.0f);  // scaled lo-plane: avoids f16 denormal flush
}
static __device__ __forceinline__ unsigned packh(f16 a, f16 b) {
  union { f16 f; unsigned short u; } ua, ub;
  ua.f = a; ub.f = b;
  return (unsigned)ua.u | ((unsigned)ub.u << 16);
}
union H4 { f16 f[4]; uint2 u; };

// ---------------- one-shot prep: all weight splits + enc gather + bar reset --------
struct Seg {
  const float* src; const int* idx; f16* hi; f16* lo;
  long end;  // cumulative end (elements)
  int cs, cd;
};
struct SegTab { Seg s[13]; };

__global__ void k_prep(SegTab tab, long total, unsigned* bar) {
  if (blockIdx.x == 0 && threadIdx.x < 256) {
    bar[threadIdx.x] = 0;
    bar[threadIdx.x + 256] = 0;
  }
  for (long pos = (long)blockIdx.x * 256 + threadIdx.x; pos < total;
       pos += (long)gridDim.x * 256) {
    long start = 0; int si = 0;
    while (pos >= tab.s[si].end) { start = tab.s[si].end; ++si; }
    const Seg g = tab.s[si];
    long local = pos - start;
    float v;
    if (g.cd == 320) {
      unsigned l32 = (unsigned)local;
      unsigned r = l32 / 320u, c = l32 - r * 320u;
      long row = g.idx ? (long)g.idx[r] : (long)r;
      v = (c < 300u) ? g.src[row * 300 + c] : 0.0f;
    } else {
      v = g.src[local];
    }
    split2(v, &g.hi[local], &g.lo[local]);
  }
}

// ---------------- split-f16 GEMM: C[M,N] = A[M,K] @ B[N,K]^T (+bias) --------------
// register-prefetch K-loop (load tile k+1 into regs right after publishing tile k
// to LDS, overlapping the MFMA block) — 2 barriers per k-step.
template <int BM>
__global__ __launch_bounds__(256, 1) void k_gemm(
    const f16* __restrict__ Ahi, const f16* __restrict__ Alo,
    const f16* __restrict__ Bhi, const f16* __restrict__ Blo,
    const float* __restrict__ bias, float* __restrict__ C,
    int M, int N, int K, long aB, long bB, long cB) {
  constexpr int MF = (BM == 128) ? 4 : 2;
  constexpr int NF = (BM == 128) ? 4 : 2;
  constexpr int ACH = BM * 8 / 256;  // A chunks per thread per plane (4 or 1)
  __shared__ f16 sA[2][BM][72];
  __shared__ f16 sB[2][128][72];

  const int tid = threadIdx.x;
  const int wid = tid >> 6, lane = tid & 63;
  const int ln = lane & 15, l4 = lane >> 4;
  const int m0 = blockIdx.y * BM;
  const int n0 = blockIdx.x * 128;
  const int z = blockIdx.z;
  const f16* pA[2] = {Ahi + (long)z * aB, Alo + (long)z * aB};
  const f16* pB[2] = {Bhi + (long)z * bB, Blo + (long)z * bB};
  float* pC = C + (long)z * cB;

  const int wrow = (BM == 128) ? (wid >> 1) * 64 : 0;
  const int wcol = (BM == 128) ? (wid & 1) * 64 : wid * 32;

  f32x4 am[MF][NF], ax[MF][NF];
#pragma unroll
  for (int i = 0; i < MF; ++i)
#pragma unroll
    for (int j = 0; j < NF; ++j) {
      am[i][j] = (f32x4){0.f, 0.f, 0.f, 0.f};
      ax[i][j] = (f32x4){0.f, 0.f, 0.f, 0.f};
    }

  uint4 ra[2][ACH], rb[2][4];
  auto load_regs = [&](int k0) {
#pragma unroll
    for (int p = 0; p < 2; ++p) {
#pragma unroll
      for (int q = 0; q < ACH; ++q) {
        const int i = tid + q * 256;
        const int r = i >> 3, ch = i & 7;
        const int gr = m0 + r;
        uint4 v = make_uint4(0u, 0u, 0u, 0u);
        if (gr < M) v = *(const uint4*)(pA[p] + (long)gr * K + k0 + ch * 8);
        ra[p][q] = v;
      }
#pragma unroll
      for (int q = 0; q < 4; ++q) {
        const int i = tid + q * 256;
        const int r = i >> 3, ch = i & 7;
        const int gn = n0 + r;
        uint4 v = make_uint4(0u, 0u, 0u, 0u);
        if (gn < N) v = *(const uint4*)(pB[p] + (long)gn * K + k0 + ch * 8);
        rb[p][q] = v;
      }
    }
  };

  load_regs(0);
  for (int k0 = 0; k0 < K; k0 += 64) {
    __syncthreads();  // previous tile's MFMA reads done before overwrite
#pragma unroll
    for (int p = 0; p < 2; ++p) {
#pragma unroll
      for (int q = 0; q < ACH; ++q) {
        const int i = tid + q * 256;
        *(uint4*)&sA[p][i >> 3][(i & 7) * 8] = ra[p][q];
      }
#pragma unroll
      for (int q = 0; q < 4; ++q) {
        const int i = tid + q * 256;
        *(uint4*)&sB[p][i >> 3][(i & 7) * 8] = rb[p][q];
      }
    }
    __syncthreads();
    if (k0 + 64 < K) load_regs(k0 + 64);  // issue-early: overlap with MFMA
#pragma unroll
    for (int kk = 0; kk < 64; kk += 32) {
      const int kc = kk + l4 * 8;
      f16x8 ah[MF], al[MF], bh[NF], bl[NF];
#pragma unroll
      for (int i = 0; i < MF; ++i) {
        ah[i] = *(const f16x8*)&sA[0][wrow + i * 16 + ln][kc];
        al[i] = *(const f16x8*)&sA[1][wrow + i * 16 + ln][kc];
      }
#pragma unroll
      for (int j = 0; j < NF; ++j) {
        bh[j] = *(const f16x8*)&sB[0][wcol + j * 16 + ln][kc];
        bl[j] = *(const f16x8*)&sB[1][wcol + j * 16 + ln][kc];
      }
#pragma unroll
      for (int i = 0; i < MF; ++i)
#pragma unroll
        for (int j = 0; j < NF; ++j) {
          am[i][j] = mfma16(ah[i], bh[j], am[i][j]);
          ax[i][j] = mfma16(ah[i], bl[j], ax[i][j]);
          ax[i][j] = mfma16(al[i], bh[j], ax[i][j]);
        }
    }
  }
#pragma unroll
  for (int i = 0; i < MF; ++i)
#pragma unroll
    for (int j = 0; j < NF; ++j) {
      int row = m0 + wrow + i * 16 + l4 * 4;
      int col = n0 + wcol + j * 16 + ln;
      if (col < N) {
        float bv = bias ? bias[col] : 0.0f;
#pragma unroll
        for (int r = 0; r < 4; ++r)
          if (row + r < M)
            pC[(long)(row + r) * N + col] = am[i][j][r] + ax[i][j][r] * (1.0f / 2048.0f) + bv;
      }
    }
}

// ---------------- persistent bidirectional LSTM layer (v5) -------------------------
// 64 WGs (2 dirs x 32), 1 WG/CU. Whh in registers. h via sc0sc1 LLC loads/stores.
// v5: release poll runs on WAVE 0 ONLY (other waves park at s_barrier) -> 4x less
// reader pressure on the contended flag cache line.
__global__ __launch_bounds__(256, 1) void k_lstm(
    const f16* __restrict__ WhhHi, const f16* __restrict__ WhhLo,  // [2*2048][512]
    const float* __restrict__ Gx,                                  // [S*32][4096]
    f16* __restrict__ hHi, f16* __restrict__ hLo,                  // [2par][2dir][32][512]
    f16* __restrict__ oHi, f16* __restrict__ oLo,                  // [S*32][1024] or null
    float* __restrict__ hidOut, f16* __restrict__ hidOutH, f16* __restrict__ hidOutL,
    float* __restrict__ cOut,                                      // [4][32][512]
    unsigned* __restrict__ bar, int S, int layer) {
  const int tid = threadIdx.x;
  const int d = blockIdx.x >> 5;
  const int wg = blockIdx.x & 31;
  const int j0 = wg * 16;

  __shared__ f16 sHh[32][520];
  __shared__ f16 sHl[32][520];
  __shared__ float sGate[2][4][32][16];

  const int wid = tid >> 6, lane = tid & 63;
  const int gh = wid & 1, kh = wid >> 1;
  const int ln = lane & 15, lk8 = (lane >> 4) * 8;

  // persistent Whh fragments in registers (gates gh*2..gh*2+1, k-half kh)
  f16x8 wbh[2][8], wbl[2][8];
#pragma unroll
  for (int gl = 0; gl < 2; ++gl) {
    const long rowb = ((long)d * 2048 + (gh * 2 + gl) * 512 + j0 + ln) << 9;
#pragma unroll
    for (int ks = 0; ks < 8; ++ks) {
      const long off = rowb + (kh * 8 + ks) * 32 + lk8;
      wbh[gl][ks] = *(const f16x8*)(WhhHi + off);
      wbl[gl][ks] = *(const f16x8*)(WhhLo + off);
    }
  }

  unsigned* flags = bar + d * 64;                   // 32 flag words per direction
  const unsigned* myFlag = flags + (lane & 31);     // wave-0 poll address
  const int cb = tid >> 3;       // cell phase: batch row
  const int cj = (tid & 7) * 2;  // cell phase: col pair within owned 16
  float creg0 = 0.0f, creg1 = 0.0f;

  // zero par0 h plane (own slice) + initial flag round (wave-0 poll)
  {
    long zo = ((long)d * 32 + cb) * 512 + j0 + cj;  // par=0 plane
    unsigned zero = 0;
    char* zh = (char*)(hHi + zo);
    char* zl = (char*)(hLo + zo);
    asm volatile("global_store_dword %0, %1, off sc0 sc1" ::"v"(zh), "v"(zero) : "memory");
    asm volatile("global_store_dword %0, %1, off sc0 sc1" ::"v"(zl), "v"(zero) : "memory");
    asm volatile("s_waitcnt vmcnt(0) lgkmcnt(0)" ::: "memory");
    __builtin_amdgcn_s_barrier();
    if (wid == 0) {
      if (lane == 0) {
        unsigned one = 1u;
        asm volatile("global_store_dword %0, %1, off sc0 sc1" ::"v"(flags + wg), "v"(one)
                     : "memory");
      }
      for (;;) {
        unsigned v;
        asm volatile("global_load_dword %0, %1, off sc0 sc1" : "=v"(v) : "v"(myFlag) : "memory");
        asm volatile("s_waitcnt vmcnt(0)" ::: "memory");
        if (__all(v >= 1u)) break;
        __builtin_amdgcn_s_sleep(1);
      }
    }
    __builtin_amdgcn_s_barrier();
    __builtin_amdgcn_sched_barrier(0);
  }

  for (int t = 0; t < S; ++t) {
    const int trow = d ? (S - 1 - t) : t;
    const int par = t & 1;

    // stage h(t-1) via coherence-point loads; Gx issued AFTER (newest 4)
    uint4 hv[16];
    {
      const char* hb = (const char*)(hHi + ((long)par * 2 + d) * 32 * 512);
      const char* lb = (const char*)(hLo + ((long)par * 2 + d) * 32 * 512);
#pragma unroll
      for (int q = 0; q < 8; ++q) {
        const char* p = hb + (((long)q * 256 + tid) << 4);
        asm volatile("global_load_dwordx4 %0, %1, off sc0 sc1" : "=v"(hv[q]) : "v"(p));
      }
#pragma unroll
      for (int q = 0; q < 8; ++q) {
        const char* p = lb + (((long)q * 256 + tid) << 4);
        asm volatile("global_load_dwordx4 %0, %1, off sc0 sc1" : "=v"(hv[8 + q]) : "v"(p));
      }
    }
    fv2 gxv[4];
#pragma unroll
    for (int g = 0; g < 4; ++g) {
      const char* p = (const char*)&Gx[((long)trow * 32 + cb) * 4096 + (long)d * 2048 +
                                       g * 512 + j0 + cj];
      asm volatile("global_load_dwordx2 %0, %1, off" : "=v"(gxv[g]) : "v"(p));
    }
    asm volatile("s_waitcnt vmcnt(4)" ::: "memory");  // all 16 h loads done; Gx in flight
    __builtin_amdgcn_sched_barrier(0);
#pragma unroll
    for (int q = 0; q < 8; ++q) {
      int c = q * 256 + tid;
      *(uint4*)&sHh[c >> 6][(c & 63) * 8] = hv[q];
      *(uint4*)&sHl[c >> 6][(c & 63) * 8] = hv[8 + q];
    }
    asm volatile("s_waitcnt lgkmcnt(0)" ::: "memory");
    __builtin_amdgcn_s_barrier();  // raw barrier: Gx loads stay in flight

    // recurrent GEMM: A = h (LDS), B = Whh fragments (registers)
    f32x4 am[2][2], ax[2][2];
#pragma unroll
    for (int a = 0; a < 2; ++a)
#pragma unroll
      for (int b2 = 0; b2 < 2; ++b2) {
        am[a][b2] = (f32x4){0.f, 0.f, 0.f, 0.f};
        ax[a][b2] = (f32x4){0.f, 0.f, 0.f, 0.f};
      }
#pragma unroll
    for (int ks = 0; ks < 8; ++ks) {
      const int kc = (kh * 8 + ks) * 32 + lk8;
      f16x8 a0h = *(const f16x8*)&sHh[ln][kc];
      f16x8 a1h = *(const f16x8*)&sHh[16 + ln][kc];
      f16x8 a0l = *(const f16x8*)&sHl[ln][kc];
      f16x8 a1l = *(const f16x8*)&sHl[16 + ln][kc];
#pragma unroll
      for (int gl = 0; gl < 2; ++gl) {
        am[gl][0] = mfma16(a0h, wbh[gl][ks], am[gl][0]);
        ax[gl][0] = mfma16(a0h, wbl[gl][ks], ax[gl][0]);
        ax[gl][0] = mfma16(a0l, wbh[gl][ks], ax[gl][0]);
        am[gl][1] = mfma16(a1h, wbh[gl][ks], am[gl][1]);
        ax[gl][1] = mfma16(a1h, wbl[gl][ks], ax[gl][1]);
        ax[gl][1] = mfma16(a1l, wbh[gl][ks], ax[gl][1]);
      }
    }

#pragma unroll
    for (int gl = 0; gl < 2; ++gl) {
      const int g = gh * 2 + gl;
#pragma unroll
      for (int mf = 0; mf < 2; ++mf) {
        const int row = mf * 16 + (lane >> 4) * 4;
#pragma unroll
        for (int r = 0; r < 4; ++r)
          sGate[kh][g][row + r][ln] = am[gl][mf][r] + ax[gl][mf][r] * (1.0f / 2048.0f);
      }
    }
    asm volatile("s_waitcnt lgkmcnt(0)" ::: "memory");
    __builtin_amdgcn_s_barrier();

    // drain Gx (landed long ago, under the GEMM)
    asm volatile("s_waitcnt vmcnt(0)" ::: "memory");
    __builtin_amdgcn_sched_barrier(0);

    // cell update
    {
      float i0 = sGate[0][0][cb][cj] + sGate[1][0][cb][cj] + gxv[0][0];
      float i1 = sGate[0][0][cb][cj + 1] + sGate[1][0][cb][cj + 1] + gxv[0][1];
      float f0 = sGate[0][1][cb][cj] + sGate[1][1][cb][cj] + gxv[1][0];
      float f1 = sGate[0][1][cb][cj + 1] + sGate[1][1][cb][cj + 1] + gxv[1][1];
      float g0 = sGate[0][2][cb][cj] + sGate[1][2][cb][cj] + gxv[2][0];
      float g1 = sGate[0][2][cb][cj + 1] + sGate[1][2][cb][cj + 1] + gxv[2][1];
      float o0 = sGate[0][3][cb][cj] + sGate[1][3][cb][cj] + gxv[3][0];
      float o1 = sGate[0][3][cb][cj + 1] + sGate[1][3][cb][cj + 1] + gxv[3][1];
      float c0 = sigf(f0) * creg0 + sigf(i0) * tanhf(g0);
      float c1 = sigf(f1) * creg1 + sigf(i1) * tanhf(g1);
      creg0 = c0; creg1 = c1;
      float h0 = sigf(o0) * tanhf(c0);
      float h1 = sigf(o1) * tanhf(c1);
      f16 h0h, h0l, h1h, h1l;
      split2(h0, &h0h, &h0l);
      split2(h1, &h1h, &h1l);
      unsigned phi = packh(h0h, h1h), plo = packh(h0l, h1l);
      long ho = ((((long)(par ^ 1) * 2 + d) * 32 + cb) * 512 + j0 + cj);
      char* dh = (char*)(hHi + ho);
      char* dl = (char*)(hLo + ho);
      asm volatile("global_store_dword %0, %1, off sc0 sc1" ::"v"(dh), "v"(phi) : "memory");
      asm volatile("global_store_dword %0, %1, off sc0 sc1" ::"v"(dl), "v"(plo) : "memory");
      if (oHi) {
        long oo = ((long)trow * 32 + cb) * 1024 + (long)d * 512 + j0 + cj;
        *(unsigned*)(oHi + oo) = phi;
        *(unsigned*)(oLo + oo) = plo;
      }
      if (t == S - 1) {
        long so = (((long)layer * 2 + d) * 32 + cb) * 512 + j0 + cj;
        *(float2*)(hidOut + so) = make_float2(h0, h1);
        *(unsigned*)(hidOutH + so) = phi;
        *(unsigned*)(hidOutL + so) = plo;
        *(float2*)(cOut + so) = make_float2(c0, c1);
      }
    }

    // release: per-wave drain, WG-barrier, wave-0 publishes flag + polls, re-barrier
    asm volatile("s_waitcnt vmcnt(0) lgkmcnt(0)" ::: "memory");
    __builtin_amdgcn_s_barrier();
    const unsigned tg = (unsigned)t + 2u;
    if (wid == 0) {
      if (lane == 0) {
        asm volatile("global_store_dword %0, %1, off sc0 sc1" ::"v"(flags + wg), "v"(tg)
                     : "memory");
      }
      for (;;) {
        unsigned v;
        asm volatile("global_load_dword %0, %1, off sc0 sc1" : "=v"(v) : "v"(myFlag) : "memory");
        asm volatile("s_waitcnt vmcnt(0)" ::: "memory");
        if (__all(v >= tg)) break;
        __builtin_amdgcn_s_sleep(1);
      }
    }
    __builtin_amdgcn_s_barrier();
    __builtin_amdgcn_sched_barrier(0);
  }
}

// ---------------- decoder LSTM layer body ------------------------------------------
// sub in [0,64): d = sub>>5, jt = sub&31 (16 j-cols). warp = one gate.
template <int XK, bool GATHER>
static __device__ __forceinline__ void dec_body(
    int sub, const int* __restrict__ tok, const float* __restrict__ emb,
    const f16* __restrict__ xH, const f16* __restrict__ xL,
    const f16* __restrict__ WihH, const f16* __restrict__ WihL,
    const f16* __restrict__ WhhH, const f16* __restrict__ WhhL,
    const float* __restrict__ bias,
    const f16* __restrict__ dhInH, const f16* __restrict__ dhInL,
    f16* __restrict__ dhOutH, f16* __restrict__ dhOutL,
    float* __restrict__ cDec, f16* __restrict__ xoH, f16* __restrict__ xoL,
    int layer, f16 (&sA)[2][32][72], f16 (&sB)[2][64][72], float (&sGate)[4][32][17]) {
  const int tid = threadIdx.x;
  const int d = sub >> 5;
  const int jt = sub & 31;
  const int s = layer * 2 + d;

  const int wid = tid >> 6, lane = tid & 63;
  const int ln = lane & 15, l4 = lane >> 4;
  const int ar = tid >> 3, ach = tid & 7;
  constexpr int NK = XK / 64 + 8;

  int tk = 0;
  if (GATHER) tk = tok[ar];

  f32x4 am[2], ax[2];
#pragma unroll
  for (int i = 0; i < 2; ++i) {
    am[i] = (f32x4){0.f, 0.f, 0.f, 0.f};
    ax[i] = (f32x4){0.f, 0.f, 0.f, 0.f};
  }

  uint4 ra0, ra1, rb[4];
  float gaf[8];

  auto load_regs = [&](int k) {
    const int k0 = k * 64;
    if (k0 < XK) {
      if (GATHER) {
        const float* rowp = emb + (long)tk * 300;
        const int c4 = k0 + ach * 8;
#pragma unroll
        for (int h = 0; h < 2; ++h) {
          float4 v = make_float4(0.f, 0.f, 0.f, 0.f);
          if (c4 + h * 4 < 300) v = *(const float4*)(rowp + c4 + h * 4);
          gaf[h * 4 + 0] = v.x; gaf[h * 4 + 1] = v.y;
          gaf[h * 4 + 2] = v.z; gaf[h * 4 + 3] = v.w;
        }
      } else {
        ra0 = *(const uint4*)(xH + (long)ar * XK + k0 + ach * 8);
        ra1 = *(const uint4*)(xL + (long)ar * XK + k0 + ach * 8);
      }
    } else {
      const int hk = k0 - XK;
      ra0 = *(const uint4*)(dhInH + ((long)s * 32 + ar) * 512 + hk + ach * 8);
      ra1 = *(const uint4*)(dhInL + ((long)s * 32 + ar) * 512 + hk + ach * 8);
    }
#pragma unroll
    for (int q = 0; q < 2; ++q) {
      const int i = tid + q * 256;
      const int r = i >> 3, ch = i & 7;  // r in [0,64): gate = r>>4, col = r&15
      const long srow = (long)d * 2048 + (r >> 4) * 512 + jt * 16 + (r & 15);
      if (k0 < XK) {
        rb[q * 2] = *(const uint4*)(WihH + srow * XK + k0 + ch * 8);
        rb[q * 2 + 1] = *(const uint4*)(WihL + srow * XK + k0 + ch * 8);
      } else {
        const int hk = k0 - XK;
        rb[q * 2] = *(const uint4*)(WhhH + srow * 512 + hk + ch * 8);
        rb[q * 2 + 1] = *(const uint4*)(WhhL + srow * 512 + hk + ch * 8);
      }
    }
  };

  load_regs(0);
  for (int k = 0; k < NK; ++k) {
    const bool gw = GATHER && (k * 64 < XK);
    __syncthreads();
    if (gw) {
#pragma unroll
      for (int u = 0; u < 8; ++u)
        split2(gaf[u], &sA[0][ar][ach * 8 + u], &sA[1][ar][ach * 8 + u]);
    } else {
      *(uint4*)&sA[0][ar][ach * 8] = ra0;
      *(uint4*)&sA[1][ar][ach * 8] = ra1;
    }
#pragma unroll
    for (int q = 0; q < 2; ++q) {
      const int i = tid + q * 256;
      const int r = i >> 3, ch = i & 7;
      *(uint4*)&sB[0][r][ch * 8] = rb[q * 2];
      *(uint4*)&sB[1][r][ch * 8] = rb[q * 2 + 1];
    }
    __syncthreads();
    if (k + 1 < NK) load_regs(k + 1);  // issue-early: overlap next tile with MFMA
#pragma unroll
    for (int kk = 0; kk < 64; kk += 32) {
      const int kc = kk + l4 * 8;
      f16x8 a0h = *(const f16x8*)&sA[0][ln][kc];
      f16x8 a1h = *(const f16x8*)&sA[0][16 + ln][kc];
      f16x8 a0l = *(const f16x8*)&sA[1][ln][kc];
      f16x8 a1l = *(const f16x8*)&sA[1][16 + ln][kc];
      f16x8 bh = *(const f16x8*)&sB[0][wid * 16 + ln][kc];
      f16x8 bl = *(const f16x8*)&sB[1][wid * 16 + ln][kc];
      am[0] = mfma16(a0h, bh, am[0]);
      ax[0] = mfma16(a0h, bl, ax[0]);
      ax[0] = mfma16(a0l, bh, ax[0]);
      am[1] = mfma16(a1h, bh, am[1]);
      ax[1] = mfma16(a1h, bl, ax[1]);
      ax[1] = mfma16(a1l, bh, ax[1]);
    }
  }

  // deposit gates: warp wid holds gate wid for 16 j x 32 b
#pragma unroll
  for (int i2 = 0; i2 < 2; ++i2)
#pragma unroll
    for (int r = 0; r < 4; ++r)
      sGate[wid][i2 * 16 + l4 * 4 + r][ln] = am[i2][r] + ax[i2][r] * (1.0f / 2048.0f);
  __syncthreads();

  // cell update: thread owns (b, 2 consecutive j)
  {
    const int b = tid >> 3, cj = (tid & 7) * 2;
    const int j = jt * 16 + cj;
    float iv0 = sGate[0][b][cj] + bias[d * 2048 + j];
    float iv1 = sGate[0][b][cj + 1] + bias[d * 2048 + j + 1];
    float fv0 = sGate[1][b][cj] + bias[d * 2048 + 512 + j];
    float fv1 = sGate[1][b][cj + 1] + bias[d * 2048 + 512 + j + 1];
    float gv0 = sGate[2][b][cj] + bias[d * 2048 + 1024 + j];
    float gv1 = sGate[2][b][cj + 1] + bias[d * 2048 + 1024 + j + 1];
    float ov0 = sGate[3][b][cj] + bias[d * 2048 + 1536 + j];
    float ov1 = sGate[3][b][cj + 1] + bias[d * 2048 + 1536 + j + 1];
    long co = ((long)s * 32 + b) * 512 + j;
    float2 cold = *(const float2*)&cDec[co];
    float c0 = sigf(fv0) * cold.x + sigf(iv0) * tanhf(gv0);
    float c1 = sigf(fv1) * cold.y + sigf(iv1) * tanhf(gv1);
    *(float2*)&cDec[co] = make_float2(c0, c1);
    float h0 = sigf(ov0) * tanhf(c0);
    float h1 = sigf(ov1) * tanhf(c1);
    f16 h0h, h0l, h1h, h1l;
    split2(h0, &h0h, &h0l);
    split2(h1, &h1h, &h1l);
    unsigned phi = packh(h0h, h1h), plo = packh(h0l, h1l);
    *(unsigned*)&dhOutH[co] = phi;
    *(unsigned*)&dhOutL[co] = plo;
    long xo = (long)b * 1024 + d * 512 + j;
    *(unsigned*)&xoH[xo] = phi;
    *(unsigned*)&xoL[xo] = plo;
  }
}

// ---------------- fused decoder LSTM step (64 blocks; standalone dispatch) ---------
template <int XK, bool GATHER>
__global__ __launch_bounds__(256, 1) void k_dec(
    const int* __restrict__ tok, const float* __restrict__ emb,
    const f16* __restrict__ xH, const f16* __restrict__ xL,
    const f16* __restrict__ WihH, const f16* __restrict__ WihL,
    const f16* __restrict__ WhhH, const f16* __restrict__ WhhL,
    const float* __restrict__ bias,
    const f16* __restrict__ dhInH, const f16* __restrict__ dhInL,
    f16* __restrict__ dhOutH, f16* __restrict__ dhOutL,
    float* __restrict__ cDec, f16* __restrict__ xoH, f16* __restrict__ xoL,
    int layer) {
  __shared__ f16 sA[2][32][72];
  __shared__ f16 sB[2][64][72];
  __shared__ float sGate[4][32][17];
  dec_body<XK, GATHER>(blockIdx.x, tok, emb, xH, xL, WihH, WihL, WhhH, WhhL, bias,
                       dhInH, dhInL, dhOutH, dhOutL, cDec, xoH, xoL, layer, sA, sB,
                       sGate);
}

// ---------------- pred GEMM: C[32,50000] = x2[32,1024] @ predW^T + b ---------------
// v3: A staged in two K-halves (66 KB LDS -> 2 blocks/CU -> all 391 blocks resident
// in one wave + 2x MLP on the B stream). B straight into MFMA register fragments,
// quad-buffered 3 slices deep; barrier-free inner loop.
__global__ __launch_bounds__(256, 2) void k_pred(
    const f16* __restrict__ xH, const f16* __restrict__ xL,    // [32][1024]
    const f16* __restrict__ BH, const f16* __restrict__ BL,    // [50000][1024]
    const float* __restrict__ bias, float* __restrict__ C) {   // [32][50000]
  __shared__ f16 sAh[32][520];
  __shared__ f16 sAl[32][520];
  const int tid = threadIdx.x;

  auto stageA = [&](int koff) {
#pragma unroll
    for (int q = 0; q < 8; ++q) {
      int idx = tid + q * 256;          // 2048 chunks of 8 f16
      int r = idx >> 6, c8 = idx & 63;  // row, 8-col chunk within half
      *(uint4*)&sAh[r][c8 * 8] = *(const uint4*)(xH + r * 1024 + koff + c8 * 8);
      *(uint4*)&sAl[r][c8 * 8] = *(const uint4*)(xL + r * 1024 + koff + c8 * 8);
    }
  };

  const int wid = tid >> 6, lane = tid & 63;
  const int ln = lane & 15, l4 = lane >> 4;
  const int n0 = blockIdx.x * 128 + wid * 32;

  const int row0 = n0 + ln, row1 = n0 + 16 + ln;
  const f16* pbh0 = BH + (long)(row0 < 50000 ? row0 : 0) * 1024 + l4 * 8;
  const f16* pbl0 = BL + (long)(row0 < 50000 ? row0 : 0) * 1024 + l4 * 8;
  const f16* pbh1 = BH + (long)(row1 < 50000 ? row1 : 0) * 1024 + l4 * 8;
  const f16* pbl1 = BL + (long)(row1 < 50000 ? row1 : 0) * 1024 + l4 * 8;

  f32x4 am[2][2], ax[2][2];
#pragma unroll
  for (int i = 0; i < 2; ++i)
#pragma unroll
    for (int j = 0; j < 2; ++j) {
      am[i][j] = (f32x4){0.f, 0.f, 0.f, 0.f};
      ax[i][j] = (f32x4){0.f, 0.f, 0.f, 0.f};
    }

  f16x8 b0[4], b1[4], b2[4], b3[4];
  auto loadB = [&](int s, f16x8* buf) {
    const long o = (long)s * 32;
    buf[0] = *(const f16x8*)(pbh0 + o);
    buf[1] = *(const f16x8*)(pbl0 + o);
    buf[2] = *(const f16x8*)(pbh1 + o);
    buf[3] = *(const f16x8*)(pbl1 + o);
  };
  auto comp = [&](int s, const f16x8* buf) {
    const int kc = (s & 15) * 32 + l4 * 8;  // LDS offset within current half
    f16x8 a0h = *(const f16x8*)&sAh[ln][kc];
    f16x8 a1h = *(const f16x8*)&sAh[16 + ln][kc];
    f16x8 a0l = *(const f16x8*)&sAl[ln][kc];
    f16x8 a1l = *(const f16x8*)&sAl[16 + ln][kc];
    am[0][0] = mfma16(a0h, buf[0], am[0][0]);
    ax[0][0] = mfma16(a0h, buf[1], ax[0][0]);
    ax[0][0] = mfma16(a0l, buf[0], ax[0][0]);
    am[1][0] = mfma16(a1h, buf[0], am[1][0]);
    ax[1][0] = mfma16(a1h, buf[1], ax[1][0]);
    ax[1][0] = mfma16(a1l, buf[0], ax[1][0]);
    am[0][1] = mfma16(a0h, buf[2], am[0][1]);
    ax[0][1] = mfma16(a0h, buf[3], ax[0][1]);
    ax[0][1] = mfma16(a0l, buf[2], ax[0][1]);
    am[1][1] = mfma16(a1h, buf[2], am[1][1]);
    ax[1][1] = mfma16(a1h, buf[3], ax[1][1]);
    ax[1][1] = mfma16(a1l, buf[2], ax[1][1]);
  };

  stageA(0);
  loadB(0, b0);
  loadB(1, b1);
  loadB(2, b2);
  __syncthreads();
#pragma unroll
  for (int h = 0; h < 2; ++h) {
    if (h) {
      __syncthreads();  // all warps done reading half 0
      stageA(512);
      __syncthreads();
    }
#pragma unroll 1
    for (int s = h * 16; s < h * 16 + 16; s += 4) {
      loadB(s + 3, b3);  // over-read past slice 31 stays inside ws planes: harmless
      comp(s, b0);
      loadB(s + 4, b0);
      comp(s + 1, b1);
      loadB(s + 5, b1);
      comp(s + 2, b2);
      loadB(s + 6, b2);
      comp(s + 3, b3);
    }
  }

#pragma unroll
  for (int j = 0; j < 2; ++j) {
    const int col = n0 + j * 16 + ln;
    if (col < 50000) {
      const float bv = bias[col];
#pragma unroll
      for (int i = 0; i < 2; ++i)
#pragma unroll
        for (int r = 0; r < 4; ++r) {
          const int row = i * 16 + l4 * 4 + r;
          C[(long)row * 50000 + col] = am[i][j][r] + ax[i][j][r] * (1.0f / 2048.0f) + bv;
        }
    }
  }
}

// ---------------- VAE elementwise (adds mu/lv biases) -------------------------------
__global__ void k_vae(const float* __restrict__ mlOut, const float* __restrict__ mub,
                      const float* __restrict__ lvb, const float* __restrict__ zn,
                      float* __restrict__ outMu, float* __restrict__ outLv,
                      float* __restrict__ outZ, f16* __restrict__ zHi,
                      f16* __restrict__ zLo) {
  int i = blockIdx.x * 256 + threadIdx.x;
  if (i >= 4 * 32 * 512) return;
  int bj = i & (32 * 512 - 1);
  int j = i & 511;
  float m = mlOut[i] + mub[j];
  float l = mlOut[65536 + i] + lvb[j];
  float z = zn[bj] * expf(0.5f * l) + m;
  outMu[i] = m;
  outLv[i] = l;
  outZ[i] = z;
  split2(z, &zHi[i], &zLo[i]);
}

// ---------------- decoder init ------------------------------------------------------
__global__ void k_decinit(const float* __restrict__ hInit, const float* __restrict__ cEnc,
                          const int* __restrict__ summary, f16* __restrict__ dhHi,
                          f16* __restrict__ dhLo, float* __restrict__ cDec,
                          int* __restrict__ tok) {
  int i = blockIdx.x * 256 + threadIdx.x;
  if (i < 4 * 32 * 512) {
    split2(hInit[i], &dhHi[i], &dhLo[i]);
    cDec[i] = cEnc[i];
  }
  if (i < 32) tok[i] = summary[i];  // summary[0][b]
}

// ---------------- fused log-softmax + argmax (one WG per batch row) -----------------
__global__ __launch_bounds__(256) void k_lsm(const float* __restrict__ logits,
                                             float* __restrict__ outs,
                                             int* __restrict__ tok, int t) {
  const int b = blockIdx.x;
  const int tid = threadIdx.x;
  const float* lg = logits + (long)b * 50000;
  float m = -INFINITY, s = 0.0f;
  int am = 0;
  for (int v = tid; v < 50000; v += 256) {
    float x = lg[v];
    if (x > m) {
      s = s * expf(m - x) + 1.0f;
      m = x;
      am = v;
    } else {
      s += expf(x - m);
    }
  }
  __shared__ float sm[256], ss[256];
  __shared__ int sa[256];
  sm[tid] = m; ss[tid] = s; sa[tid] = am;
  __syncthreads();
  for (int o = 128; o > 0; o >>= 1) {
    if (tid < o) {
      float m2 = sm[tid + o], s2 = ss[tid + o];
      int a2 = sa[tid + o];
      float m1 = sm[tid], s1 = ss[tid];
      int a1 = sa[tid];
      if (m2 > m1 || (m2 == m1 && a2 < a1)) {
        sm[tid] = m2; ss[tid] = s2 + s1 * expf(m1 - m2); sa[tid] = a2;
      } else {
        ss[tid] = s1 + s2 * expf(m2 - m1);
      }
    }
    __syncthreads();
  }
  float lse = sm[0] + logf(ss[0]);
  float* ob = outs + ((long)t * 32 + b) * 50000;
  for (int v = tid; v < 50000; v += 256) ob[v] = lg[v] - lse;
  if (tid == 0) tok[b] = sa[0];
}

// ====================================================================================
extern "C" void kernel_launch(void* const* d_in, const int* in_sizes, int n_in,
                              void* d_out, int out_size, void* d_ws, size_t ws_size,
                              hipStream_t stream) {
  const int* article = (const int*)d_in[0];
  const int* summary = (const int*)d_in[1];
  const float* z_noise = (const float*)d_in[2];
  const float* enc_emb = (const float*)d_in[3];
  const float* e0Wih = (const float*)d_in[4];
  const float* e0Whh = (const float*)d_in[5];
  const float* e0b = (const float*)d_in[6];
  const float* e1Wih = (const float*)d_in[7];
  const float* e1Whh = (const float*)d_in[8];
  const float* e1b = (const float*)d_in[9];
  const float* muW = (const float*)d_in[10];
  const float* mub = (const float*)d_in[11];
  const float* lvW = (const float*)d_in[12];
  const float* lvb = (const float*)d_in[13];
  const float* dhW = (const float*)d_in[14];
  const float* dhb = (const float*)d_in[15];
  const float* dec_emb = (const float*)d_in[16];
  const float* d0Wih = (const float*)d_in[17];
  const float* d0Whh = (const float*)d_in[18];
  const float* d0b = (const float*)d_in[19];
  const float* d1Wih = (const float*)d_in[20];
  const float* d1Whh = (const float*)d_in[21];
  const float* d1b = (const float*)d_in[22];
  const float* predW = (const float*)d_in[23];
  const float* predb = (const float*)d_in[24];
  float* out = (float*)d_out;
  (void)in_sizes; (void)n_in; (void)out_size; (void)ws_size;

  char* w = (char*)d_ws;
  size_t off = 0;
  auto alloc = [&](size_t bytes) -> void* {
    void* p = w + off;
    off += (bytes + 255) & ~(size_t)255;
    return p;
  };

  f16* e0WihH = (f16*)alloc(4096L * 320 * 2);
  f16* e0WihL = (f16*)alloc(4096L * 320 * 2);
  f16* e0WhhH = (f16*)alloc(4096L * 512 * 2);
  f16* e0WhhL = (f16*)alloc(4096L * 512 * 2);
  f16* e1WihH = (f16*)alloc(4096L * 1024 * 2);
  f16* e1WihL = (f16*)alloc(4096L * 1024 * 2);
  f16* e1WhhH = (f16*)alloc(4096L * 512 * 2);
  f16* e1WhhL = (f16*)alloc(4096L * 512 * 2);
  f16* d0WihH = (f16*)alloc(4096L * 320 * 2);
  f16* d0WihL = (f16*)alloc(4096L * 320 * 2);
  f16* d0WhhH = (f16*)alloc(4096L * 512 * 2);
  f16* d0WhhL = (f16*)alloc(4096L * 512 * 2);
  f16* d1WihH = (f16*)alloc(4096L * 1024 * 2);
  f16* d1WihL = (f16*)alloc(4096L * 1024 * 2);
  f16* d1WhhH = (f16*)alloc(4096L * 512 * 2);
  f16* d1WhhL = (f16*)alloc(4096L * 512 * 2);
  f16* mlWH = (f16*)alloc(2L * 262144 * 2);   // muW hi | lvW hi
  f16* mlWL = (f16*)alloc(2L * 262144 * 2);
  f16* dhWH = (f16*)alloc(512L * 512 * 2);
  f16* dhWL = (f16*)alloc(512L * 512 * 2);
  f16* predH = (f16*)alloc(50000L * 1024 * 2);
  f16* predL = (f16*)alloc(50000L * 1024 * 2);
  f16* embH = (f16*)alloc(12800L * 320 * 2);
  f16* embL = (f16*)alloc(12800L * 320 * 2);
  f16* o0H = (f16*)alloc(12800L * 1024 * 2);
  f16* o0L = (f16*)alloc(12800L * 1024 * 2);
  float* Gx = (float*)alloc(12800L * 4096 * 4);
  f16* hEncH = (f16*)alloc(2L * 2 * 32 * 512 * 2);
  f16* hEncL = (f16*)alloc(2L * 2 * 32 * 512 * 2);
  float* hid = (float*)alloc(128L * 512 * 4);
  float* cEnc = (float*)alloc(128L * 512 * 4);
  f16* hidH = (f16*)alloc(128L * 512 * 2);
  f16* hidL = (f16*)alloc(128L * 512 * 2);
  float* mlOut = (float*)alloc(2L * 65536 * 4);  // mu | lv (pre-bias)
  f16* zH = (f16*)alloc(128L * 512 * 2);
  f16* zL = (f16*)alloc(128L * 512 * 2);
  float* hInit = (float*)alloc(128L * 512 * 4);
  f16* dhH = (f16*)alloc(2L * 65536 * 2);  // [2 par][4][32][512]
  f16* dhL = (f16*)alloc(2L * 65536 * 2);
  float* cDec = (float*)alloc(4L * 32 * 512 * 4);
  f16* x1H = (f16*)alloc(32L * 1024 * 2);
  f16* x1L = (f16*)alloc(32L * 1024 * 2);
  f16* x2H = (f16*)alloc(32L * 1024 * 2);
  f16* x2L = (f16*)alloc(32L * 1024 * 2);
  float* logits = (float*)alloc(32L * 50000 * 4);
  int* tok = (int*)alloc(256);
  unsigned* bar = (unsigned*)alloc(2048);  // 512 words of flags

  // ---- single prep kernel: all splits + enc gather + bar reset ----
  SegTab tab;
  long cum = 0;
  int si = 0;
  auto seg = [&](const float* src, const int* idx, f16* hi, f16* lo, long rows, int cs,
                 int cd) {
    cum += rows * cd;
    tab.s[si++] = Seg{src, idx, hi, lo, cum, cs, cd};
  };
  seg(e0Wih, nullptr, e0WihH, e0WihL, 4096, 300, 320);
  seg(e0Whh, nullptr, e0WhhH, e0WhhL, 4096, 512, 512);
  seg(e1Wih, nullptr, e1WihH, e1WihL, 4096, 1024, 1024);
  seg(e1Whh, nullptr, e1WhhH, e1WhhL, 4096, 512, 512);
  seg(d0Wih, nullptr, d0WihH, d0WihL, 4096, 300, 320);
  seg(d0Whh, nullptr, d0WhhH, d0WhhL, 4096, 512, 512);
  seg(d1Wih, nullptr, d1WihH, d1WihL, 4096, 1024, 1024);
  seg(d1Whh, nullptr, d1WhhH, d1WhhL, 4096, 512, 512);
  seg(muW, nullptr, mlWH, mlWL, 512, 512, 512);
  seg(lvW, nullptr, mlWH + 262144, mlWL + 262144, 512, 512, 512);
  seg(dhW, nullptr, dhWH, dhWL, 512, 512, 512);
  seg(predW, nullptr, predH, predL, 50000, 1024, 1024);
  seg(enc_emb, article, embH, embL, 12800, 300, 320);
  k_prep<<<8192, 256, 0, stream>>>(tab, cum, bar);

  // ---- encoder ----
  k_gemm<128><<<dim3(32, 100, 1), 256, 0, stream>>>(embH, embL, e0WihH, e0WihL, e0b, Gx,
                                                    12800, 4096, 320, 0, 0, 0);
  k_lstm<<<64, 256, 0, stream>>>(e0WhhH, e0WhhL, Gx, hEncH, hEncL, o0H, o0L, hid, hidH,
                                 hidL, cEnc, bar, 400, 0);
  k_gemm<128><<<dim3(32, 100, 1), 256, 0, stream>>>(o0H, o0L, e1WihH, e1WihL, e1b, Gx,
                                                    12800, 4096, 1024, 0, 0, 0);
  k_lstm<<<64, 256, 0, stream>>>(e1WhhH, e1WhhL, Gx, hEncH, hEncL, (f16*)nullptr,
                                 (f16*)nullptr, hid, hidH, hidL, cEnc, bar + 128, 400, 1);

  // ---- VAE (mu+lv batched) ----
  k_gemm<32><<<dim3(4, 4, 2), 256, 0, stream>>>(hidH, hidL, mlWH, mlWL,
                                                (const float*)nullptr, mlOut, 128, 512,
                                                512, 0, 262144, 65536);
  k_vae<<<256, 256, 0, stream>>>(mlOut, mub, lvb, z_noise, out + 24000000L,
                                 out + 24065536L, out + 24131072L, zH, zL);
  k_gemm<32><<<dim3(4, 4, 1), 256, 0, stream>>>(zH, zL, dhWH, dhWL, dhb, hInit, 128, 512,
                                                512, 0, 0, 0);
  k_decinit<<<256, 256, 0, stream>>>(hInit, cEnc, summary, dhH, dhL, cDec, tok);

  // ---- decoder greedy loop (4 nodes/step) ----
  for (int t = 0; t < 15; ++t) {
    int par = t & 1;
    f16* dIH = dhH + (long)par * 65536;
    f16* dIL = dhL + (long)par * 65536;
    f16* dOH = dhH + (long)(par ^ 1) * 65536;
    f16* dOL = dhL + (long)(par ^ 1) * 65536;
    k_dec<320, true><<<64, 256, 0, stream>>>(tok, dec_emb, (const f16*)nullptr,
                                             (const f16*)nullptr, d0WihH, d0WihL, d0WhhH,
                                             d0WhhL, d0b, dIH, dIL, dOH, dOL, cDec, x1H,
                                             x1L, 0);
    k_dec<1024, false><<<64, 256, 0, stream>>>((const int*)nullptr, (const float*)nullptr,
                                               x1H, x1L, d1WihH, d1WihL, d1WhhH, d1WhhL,
                                               d1b, dIH, dIL, dOH, dOL, cDec, x2H, x2L,
                                               1);
    k_pred<<<391, 256, 0, stream>>>(x2H, x2L, predH, predL, predb, logits);
    k_lsm<<<32, 256, 0, stream>>>(logits, out, tok, t);
  }
}

// Round 12
// 6580.023 us; speedup vs baseline: 1.1485x; 1.1485x over previous
//
#include <hip/hip_runtime.h>
#include <math.h>

typedef _Float16 f16;
typedef __attribute__((__ext_vector_type__(8))) _Float16 f16x8;
typedef __attribute__((__ext_vector_type__(4))) float f32x4;
typedef __attribute__((__ext_vector_type__(2))) float fv2;

static __device__ __forceinline__ f32x4 mfma16(f16x8 a, f16x8 b, f32x4 c) {
  return __builtin_amdgcn_mfma_f32_16x16x32_f16(a, b, c, 0, 0, 0);
}
static __device__ __forceinline__ float sigf(float x) { return 1.0f / (1.0f + expf(-x)); }
static __device__ __forceinline__ void split2(float v, f16* hi, f16* lo) {
  f16 h = (f16)v;
  *hi = h;
  *lo = (f16)((v - (float)h) * 2048.0f);  // scaled lo-plane: avoids f16 denormal flush
}
static __device__ __forceinline__ unsigned packh(f16 a, f16 b) {
  union { f16 f; unsigned short u; } ua, ub;
  ua.f = a; ub.f = b;
  return (unsigned)ua.u | ((unsigned)ub.u << 16);
}
union H4 { f16 f[4]; uint2 u; };

// ---------------- one-shot prep: all weight splits + enc gather + bar reset --------
struct Seg {
  const float* src; const int* idx; f16* hi; f16* lo;
  long end;  // cumulative end (elements)
  int cs, cd;
};
struct SegTab { Seg s[13]; };

__global__ void k_prep(SegTab tab, long total, unsigned* bar) {
  if (blockIdx.x == 0 && threadIdx.x < 256) {
    bar[threadIdx.x] = 0;
    bar[threadIdx.x + 256] = 0;
  }
  for (long pos = (long)blockIdx.x * 256 + threadIdx.x; pos < total;
       pos += (long)gridDim.x * 256) {
    long start = 0; int si = 0;
    while (pos >= tab.s[si].end) { start = tab.s[si].end; ++si; }
    const Seg g = tab.s[si];
    long local = pos - start;
    float v;
    if (g.cd == 320) {
      unsigned l32 = (unsigned)local;
      unsigned r = l32 / 320u, c = l32 - r * 320u;
      long row = g.idx ? (long)g.idx[r] : (long)r;
      v = (c < 300u) ? g.src[row * 300 + c] : 0.0f;
    } else {
      v = g.src[local];
    }
    split2(v, &g.hi[local], &g.lo[local]);
  }
}

// ---------------- split-f16 GEMM: C[M,N] = A[M,K] @ B[N,K]^T (+bias) --------------
// register-prefetch K-loop (load tile k+1 into regs right after publishing tile k
// to LDS, overlapping the MFMA block) — 2 barriers per k-step.
template <int BM>
__global__ __launch_bounds__(256, 1) void k_gemm(
    const f16* __restrict__ Ahi, const f16* __restrict__ Alo,
    const f16* __restrict__ Bhi, const f16* __restrict__ Blo,
    const float* __restrict__ bias, float* __restrict__ C,
    int M, int N, int K, long aB, long bB, long cB) {
  constexpr int MF = (BM == 128) ? 4 : 2;
  constexpr int NF = (BM == 128) ? 4 : 2;
  constexpr int ACH = BM * 8 / 256;  // A chunks per thread per plane (4 or 1)
  __shared__ f16 sA[2][BM][72];
  __shared__ f16 sB[2][128][72];

  const int tid = threadIdx.x;
  const int wid = tid >> 6, lane = tid & 63;
  const int ln = lane & 15, l4 = lane >> 4;
  const int m0 = blockIdx.y * BM;
  const int n0 = blockIdx.x * 128;
  const int z = blockIdx.z;
  const f16* pA[2] = {Ahi + (long)z * aB, Alo + (long)z * aB};
  const f16* pB[2] = {Bhi + (long)z * bB, Blo + (long)z * bB};
  float* pC = C + (long)z * cB;

  const int wrow = (BM == 128) ? (wid >> 1) * 64 : 0;
  const int wcol = (BM == 128) ? (wid & 1) * 64 : wid * 32;

  f32x4 am[MF][NF], ax[MF][NF];
#pragma unroll
  for (int i = 0; i < MF; ++i)
#pragma unroll
    for (int j = 0; j < NF; ++j) {
      am[i][j] = (f32x4){0.f, 0.f, 0.f, 0.f};
      ax[i][j] = (f32x4){0.f, 0.f, 0.f, 0.f};
    }

  uint4 ra[2][ACH], rb[2][4];
  auto load_regs = [&](int k0) {
#pragma unroll
    for (int p = 0; p < 2; ++p) {
#pragma unroll
      for (int q = 0; q < ACH; ++q) {
        const int i = tid + q * 256;
        const int r = i >> 3, ch = i & 7;
        const int gr = m0 + r;
        uint4 v = make_uint4(0u, 0u, 0u, 0u);
        if (gr < M) v = *(const uint4*)(pA[p] + (long)gr * K + k0 + ch * 8);
        ra[p][q] = v;
      }
#pragma unroll
      for (int q = 0; q < 4; ++q) {
        const int i = tid + q * 256;
        const int r = i >> 3, ch = i & 7;
        const int gn = n0 + r;
        uint4 v = make_uint4(0u, 0u, 0u, 0u);
        if (gn < N) v = *(const uint4*)(pB[p] + (long)gn * K + k0 + ch * 8);
        rb[p][q] = v;
      }
    }
  };

  load_regs(0);
  for (int k0 = 0; k0 < K; k0 += 64) {
    __syncthreads();  // previous tile's MFMA reads done before overwrite
#pragma unroll
    for (int p = 0; p < 2; ++p) {
#pragma unroll
      for (int q = 0; q < ACH; ++q) {
        const int i = tid + q * 256;
        *(uint4*)&sA[p][i >> 3][(i & 7) * 8] = ra[p][q];
      }
#pragma unroll
      for (int q = 0; q < 4; ++q) {
        const int i = tid + q * 256;
        *(uint4*)&sB[p][i >> 3][(i & 7) * 8] = rb[p][q];
      }
    }
    __syncthreads();
    if (k0 + 64 < K) load_regs(k0 + 64);  // issue-early: overlap with MFMA
#pragma unroll
    for (int kk = 0; kk < 64; kk += 32) {
      const int kc = kk + l4 * 8;
      f16x8 ah[MF], al[MF], bh[NF], bl[NF];
#pragma unroll
      for (int i = 0; i < MF; ++i) {
        ah[i] = *(const f16x8*)&sA[0][wrow + i * 16 + ln][kc];
        al[i] = *(const f16x8*)&sA[1][wrow + i * 16 + ln][kc];
      }
#pragma unroll
      for (int j = 0; j < NF; ++j) {
        bh[j] = *(const f16x8*)&sB[0][wcol + j * 16 + ln][kc];
        bl[j] = *(const f16x8*)&sB[1][wcol + j * 16 + ln][kc];
      }
#pragma unroll
      for (int i = 0; i < MF; ++i)
#pragma unroll
        for (int j = 0; j < NF; ++j) {
          am[i][j] = mfma16(ah[i], bh[j], am[i][j]);
          ax[i][j] = mfma16(ah[i], bl[j], ax[i][j]);
          ax[i][j] = mfma16(al[i], bh[j], ax[i][j]);
        }
    }
  }
#pragma unroll
  for (int i = 0; i < MF; ++i)
#pragma unroll
    for (int j = 0; j < NF; ++j) {
      int row = m0 + wrow + i * 16 + l4 * 4;
      int col = n0 + wcol + j * 16 + ln;
      if (col < N) {
        float bv = bias ? bias[col] : 0.0f;
#pragma unroll
        for (int r = 0; r < 4; ++r)
          if (row + r < M)
            pC[(long)(row + r) * N + col] = am[i][j][r] + ax[i][j][r] * (1.0f / 2048.0f) + bv;
      }
    }
}

// ---------------- persistent bidirectional LSTM layer (v4 — R10 proven) ------------
// 64 WGs (2 dirs x 32), 1 WG/CU. Whh in registers. h via sc0sc1 LLC loads/stores.
// Gx issued AFTER h loads, waited vmcnt(4); flag-word barrier, all-thread poll.
__global__ __launch_bounds__(256, 1) void k_lstm(
    const f16* __restrict__ WhhHi, const f16* __restrict__ WhhLo,  // [2*2048][512]
    const float* __restrict__ Gx,                                  // [S*32][4096]
    f16* __restrict__ hHi, f16* __restrict__ hLo,                  // [2par][2dir][32][512]
    f16* __restrict__ oHi, f16* __restrict__ oLo,                  // [S*32][1024] or null
    float* __restrict__ hidOut, f16* __restrict__ hidOutH, f16* __restrict__ hidOutL,
    float* __restrict__ cOut,                                      // [4][32][512]
    unsigned* __restrict__ bar, int S, int layer) {
  const int tid = threadIdx.x;
  const int d = blockIdx.x >> 5;
  const int wg = blockIdx.x & 31;
  const int j0 = wg * 16;

  __shared__ f16 sHh[32][520];
  __shared__ f16 sHl[32][520];
  __shared__ float sGate[2][4][32][16];

  const int wid = tid >> 6, lane = tid & 63;
  const int gh = wid & 1, kh = wid >> 1;
  const int ln = lane & 15, lk8 = (lane >> 4) * 8;

  // persistent Whh fragments in registers (gates gh*2..gh*2+1, k-half kh)
  f16x8 wbh[2][8], wbl[2][8];
#pragma unroll
  for (int gl = 0; gl < 2; ++gl) {
    const long rowb = ((long)d * 2048 + (gh * 2 + gl) * 512 + j0 + ln) << 9;
#pragma unroll
    for (int ks = 0; ks < 8; ++ks) {
      const long off = rowb + (kh * 8 + ks) * 32 + lk8;
      wbh[gl][ks] = *(const f16x8*)(WhhHi + off);
      wbl[gl][ks] = *(const f16x8*)(WhhLo + off);
    }
  }

  unsigned* flags = bar + d * 64;             // 32 flag words per direction
  const unsigned* myFlag = flags + (tid & 31);
  const int cb = tid >> 3;       // cell phase: batch row
  const int cj = (tid & 7) * 2;  // cell phase: col pair within owned 16
  float creg0 = 0.0f, creg1 = 0.0f;

  // zero par0 h plane (own slice) + initial flag round
  {
    long zo = ((long)d * 32 + cb) * 512 + j0 + cj;  // par=0 plane
    unsigned zero = 0;
    char* zh = (char*)(hHi + zo);
    char* zl = (char*)(hLo + zo);
    asm volatile("global_store_dword %0, %1, off sc0 sc1" ::"v"(zh), "v"(zero) : "memory");
    asm volatile("global_store_dword %0, %1, off sc0 sc1" ::"v"(zl), "v"(zero) : "memory");
    asm volatile("s_waitcnt vmcnt(0) lgkmcnt(0)" ::: "memory");
    __builtin_amdgcn_s_barrier();
    if (tid == 0) {
      unsigned one = 1u;
      asm volatile("global_store_dword %0, %1, off sc0 sc1" ::"v"(flags + wg), "v"(one)
                   : "memory");
    }
    for (;;) {
      unsigned v;
      asm volatile("global_load_dword %0, %1, off sc0 sc1" : "=v"(v) : "v"(myFlag) : "memory");
      asm volatile("s_waitcnt vmcnt(0)" ::: "memory");
      if (__all(v >= 1u)) break;
      __builtin_amdgcn_s_sleep(1);
    }
    __builtin_amdgcn_sched_barrier(0);
  }

  for (int t = 0; t < S; ++t) {
    const int trow = d ? (S - 1 - t) : t;
    const int par = t & 1;

    // stage h(t-1) via coherence-point loads; Gx issued AFTER (newest 4)
    uint4 hv[16];
    {
      const char* hb = (const char*)(hHi + ((long)par * 2 + d) * 32 * 512);
      const char* lb = (const char*)(hLo + ((long)par * 2 + d) * 32 * 512);
#pragma unroll
      for (int q = 0; q < 8; ++q) {
        const char* p = hb + (((long)q * 256 + tid) << 4);
        asm volatile("global_load_dwordx4 %0, %1, off sc0 sc1" : "=v"(hv[q]) : "v"(p));
      }
#pragma unroll
      for (int q = 0; q < 8; ++q) {
        const char* p = lb + (((long)q * 256 + tid) << 4);
        asm volatile("global_load_dwordx4 %0, %1, off sc0 sc1" : "=v"(hv[8 + q]) : "v"(p));
      }
    }
    fv2 gxv[4];
#pragma unroll
    for (int g = 0; g < 4; ++g) {
      const char* p = (const char*)&Gx[((long)trow * 32 + cb) * 4096 + (long)d * 2048 +
                                       g * 512 + j0 + cj];
      asm volatile("global_load_dwordx2 %0, %1, off" : "=v"(gxv[g]) : "v"(p));
    }
    asm volatile("s_waitcnt vmcnt(4)" ::: "memory");  // all 16 h loads done; Gx in flight
    __builtin_amdgcn_sched_barrier(0);
#pragma unroll
    for (int q = 0; q < 8; ++q) {
      int c = q * 256 + tid;
      *(uint4*)&sHh[c >> 6][(c & 63) * 8] = hv[q];
      *(uint4*)&sHl[c >> 6][(c & 63) * 8] = hv[8 + q];
    }
    asm volatile("s_waitcnt lgkmcnt(0)" ::: "memory");
    __builtin_amdgcn_s_barrier();  // raw barrier: Gx loads stay in flight

    // recurrent GEMM: A = h (LDS), B = Whh fragments (registers)
    f32x4 am[2][2], ax[2][2];
#pragma unroll
    for (int a = 0; a < 2; ++a)
#pragma unroll
      for (int b2 = 0; b2 < 2; ++b2) {
        am[a][b2] = (f32x4){0.f, 0.f, 0.f, 0.f};
        ax[a][b2] = (f32x4){0.f, 0.f, 0.f, 0.f};
      }
#pragma unroll
    for (int ks = 0; ks < 8; ++ks) {
      const int kc = (kh * 8 + ks) * 32 + lk8;
      f16x8 a0h = *(const f16x8*)&sHh[ln][kc];
      f16x8 a1h = *(const f16x8*)&sHh[16 + ln][kc];
      f16x8 a0l = *(const f16x8*)&sHl[ln][kc];
      f16x8 a1l = *(const f16x8*)&sHl[16 + ln][kc];
#pragma unroll
      for (int gl = 0; gl < 2; ++gl) {
        am[gl][0] = mfma16(a0h, wbh[gl][ks], am[gl][0]);
        ax[gl][0] = mfma16(a0h, wbl[gl][ks], ax[gl][0]);
        ax[gl][0] = mfma16(a0l, wbh[gl][ks], ax[gl][0]);
        am[gl][1] = mfma16(a1h, wbh[gl][ks], am[gl][1]);
        ax[gl][1] = mfma16(a1h, wbl[gl][ks], ax[gl][1]);
        ax[gl][1] = mfma16(a1l, wbh[gl][ks], ax[gl][1]);
      }
    }

#pragma unroll
    for (int gl = 0; gl < 2; ++gl) {
      const int g = gh * 2 + gl;
#pragma unroll
      for (int mf = 0; mf < 2; ++mf) {
        const int row = mf * 16 + (lane >> 4) * 4;
#pragma unroll
        for (int r = 0; r < 4; ++r)
          sGate[kh][g][row + r][ln] = am[gl][mf][r] + ax[gl][mf][r] * (1.0f / 2048.0f);
      }
    }
    asm volatile("s_waitcnt lgkmcnt(0)" ::: "memory");
    __builtin_amdgcn_s_barrier();

    // drain Gx (landed long ago, under the GEMM)
    asm volatile("s_waitcnt vmcnt(0)" ::: "memory");
    __builtin_amdgcn_sched_barrier(0);

    // cell update
    {
      float i0 = sGate[0][0][cb][cj] + sGate[1][0][cb][cj] + gxv[0][0];
      float i1 = sGate[0][0][cb][cj + 1] + sGate[1][0][cb][cj + 1] + gxv[0][1];
      float f0 = sGate[0][1][cb][cj] + sGate[1][1][cb][cj] + gxv[1][0];
      float f1 = sGate[0][1][cb][cj + 1] + sGate[1][1][cb][cj + 1] + gxv[1][1];
      float g0 = sGate[0][2][cb][cj] + sGate[1][2][cb][cj] + gxv[2][0];
      float g1 = sGate[0][2][cb][cj + 1] + sGate[1][2][cb][cj + 1] + gxv[2][1];
      float o0 = sGate[0][3][cb][cj] + sGate[1][3][cb][cj] + gxv[3][0];
      float o1 = sGate[0][3][cb][cj + 1] + sGate[1][3][cb][cj + 1] + gxv[3][1];
      float c0 = sigf(f0) * creg0 + sigf(i0) * tanhf(g0);
      float c1 = sigf(f1) * creg1 + sigf(i1) * tanhf(g1);
      creg0 = c0; creg1 = c1;
      float h0 = sigf(o0) * tanhf(c0);
      float h1 = sigf(o1) * tanhf(c1);
      f16 h0h, h0l, h1h, h1l;
      split2(h0, &h0h, &h0l);
      split2(h1, &h1h, &h1l);
      unsigned phi = packh(h0h, h1h), plo = packh(h0l, h1l);
      long ho = ((((long)(par ^ 1) * 2 + d) * 32 + cb) * 512 + j0 + cj);
      char* dh = (char*)(hHi + ho);
      char* dl = (char*)(hLo + ho);
      asm volatile("global_store_dword %0, %1, off sc0 sc1" ::"v"(dh), "v"(phi) : "memory");
      asm volatile("global_store_dword %0, %1, off sc0 sc1" ::"v"(dl), "v"(plo) : "memory");
      if (oHi) {
        long oo = ((long)trow * 32 + cb) * 1024 + (long)d * 512 + j0 + cj;
        *(unsigned*)(oHi + oo) = phi;
        *(unsigned*)(oLo + oo) = plo;
      }
      if (t == S - 1) {
        long so = (((long)layer * 2 + d) * 32 + cb) * 512 + j0 + cj;
        *(float2*)(hidOut + so) = make_float2(h0, h1);
        *(unsigned*)(hidOutH + so) = phi;
        *(unsigned*)(hidOutL + so) = plo;
        *(float2*)(cOut + so) = make_float2(c0, c1);
      }
    }

    // release: drain own stores, WG-barrier, publish flag, all-thread poll
    asm volatile("s_waitcnt vmcnt(0) lgkmcnt(0)" ::: "memory");
    __builtin_amdgcn_s_barrier();
    const unsigned tg = (unsigned)t + 2u;
    if (tid == 0) {
      asm volatile("global_store_dword %0, %1, off sc0 sc1" ::"v"(flags + wg), "v"(tg)
                   : "memory");
    }
    for (;;) {
      unsigned v;
      asm volatile("global_load_dword %0, %1, off sc0 sc1" : "=v"(v) : "v"(myFlag) : "memory");
      asm volatile("s_waitcnt vmcnt(0)" ::: "memory");
      if (__all(v >= tg)) break;
      __builtin_amdgcn_s_sleep(1);
    }
    __builtin_amdgcn_sched_barrier(0);
  }
}

// ---------------- decoder LSTM layer body ------------------------------------------
// sub in [0,64): d = sub>>5, jt = sub&31 (16 j-cols). warp = one gate.
template <int XK, bool GATHER>
static __device__ __forceinline__ void dec_body(
    int sub, const int* __restrict__ tok, const float* __restrict__ emb,
    const f16* __restrict__ xH, const f16* __restrict__ xL,
    const f16* __restrict__ WihH, const f16* __restrict__ WihL,
    const f16* __restrict__ WhhH, const f16* __restrict__ WhhL,
    const float* __restrict__ bias,
    const f16* __restrict__ dhInH, const f16* __restrict__ dhInL,
    f16* __restrict__ dhOutH, f16* __restrict__ dhOutL,
    float* __restrict__ cDec, f16* __restrict__ xoH, f16* __restrict__ xoL,
    int layer, f16 (&sA)[2][32][72], f16 (&sB)[2][64][72], float (&sGate)[4][32][17]) {
  const int tid = threadIdx.x;
  const int d = sub >> 5;
  const int jt = sub & 31;
  const int s = layer * 2 + d;

  const int wid = tid >> 6, lane = tid & 63;
  const int ln = lane & 15, l4 = lane >> 4;
  const int ar = tid >> 3, ach = tid & 7;
  constexpr int NK = XK / 64 + 8;

  int tk = 0;
  if (GATHER) tk = tok[ar];

  f32x4 am[2], ax[2];
#pragma unroll
  for (int i = 0; i < 2; ++i) {
    am[i] = (f32x4){0.f, 0.f, 0.f, 0.f};
    ax[i] = (f32x4){0.f, 0.f, 0.f, 0.f};
  }

  uint4 ra0, ra1, rb[4];
  float gaf[8];

  auto load_regs = [&](int k) {
    const int k0 = k * 64;
    if (k0 < XK) {
      if (GATHER) {
        const float* rowp = emb + (long)tk * 300;
        const int c4 = k0 + ach * 8;
#pragma unroll
        for (int h = 0; h < 2; ++h) {
          float4 v = make_float4(0.f, 0.f, 0.f, 0.f);
          if (c4 + h * 4 < 300) v = *(const float4*)(rowp + c4 + h * 4);
          gaf[h * 4 + 0] = v.x; gaf[h * 4 + 1] = v.y;
          gaf[h * 4 + 2] = v.z; gaf[h * 4 + 3] = v.w;
        }
      } else {
        ra0 = *(const uint4*)(xH + (long)ar * XK + k0 + ach * 8);
        ra1 = *(const uint4*)(xL + (long)ar * XK + k0 + ach * 8);
      }
    } else {
      const int hk = k0 - XK;
      ra0 = *(const uint4*)(dhInH + ((long)s * 32 + ar) * 512 + hk + ach * 8);
      ra1 = *(const uint4*)(dhInL + ((long)s * 32 + ar) * 512 + hk + ach * 8);
    }
#pragma unroll
    for (int q = 0; q < 2; ++q) {
      const int i = tid + q * 256;
      const int r = i >> 3, ch = i & 7;  // r in [0,64): gate = r>>4, col = r&15
      const long srow = (long)d * 2048 + (r >> 4) * 512 + jt * 16 + (r & 15);
      if (k0 < XK) {
        rb[q * 2] = *(const uint4*)(WihH + srow * XK + k0 + ch * 8);
        rb[q * 2 + 1] = *(const uint4*)(WihL + srow * XK + k0 + ch * 8);
      } else {
        const int hk = k0 - XK;
        rb[q * 2] = *(const uint4*)(WhhH + srow * 512 + hk + ch * 8);
        rb[q * 2 + 1] = *(const uint4*)(WhhL + srow * 512 + hk + ch * 8);
      }
    }
  };

  load_regs(0);
  for (int k = 0; k < NK; ++k) {
    const bool gw = GATHER && (k * 64 < XK);
    __syncthreads();
    if (gw) {
#pragma unroll
      for (int u = 0; u < 8; ++u)
        split2(gaf[u], &sA[0][ar][ach * 8 + u], &sA[1][ar][ach * 8 + u]);
    } else {
      *(uint4*)&sA[0][ar][ach * 8] = ra0;
      *(uint4*)&sA[1][ar][ach * 8] = ra1;
    }
#pragma unroll
    for (int q = 0; q < 2; ++q) {
      const int i = tid + q * 256;
      const int r = i >> 3, ch = i & 7;
      *(uint4*)&sB[0][r][ch * 8] = rb[q * 2];
      *(uint4*)&sB[1][r][ch * 8] = rb[q * 2 + 1];
    }
    __syncthreads();
    if (k + 1 < NK) load_regs(k + 1);  // issue-early: overlap next tile with MFMA
#pragma unroll
    for (int kk = 0; kk < 64; kk += 32) {
      const int kc = kk + l4 * 8;
      f16x8 a0h = *(const f16x8*)&sA[0][ln][kc];
      f16x8 a1h = *(const f16x8*)&sA[0][16 + ln][kc];
      f16x8 a0l = *(const f16x8*)&sA[1][ln][kc];
      f16x8 a1l = *(const f16x8*)&sA[1][16 + ln][kc];
      f16x8 bh = *(const f16x8*)&sB[0][wid * 16 + ln][kc];
      f16x8 bl = *(const f16x8*)&sB[1][wid * 16 + ln][kc];
      am[0] = mfma16(a0h, bh, am[0]);
      ax[0] = mfma16(a0h, bl, ax[0]);
      ax[0] = mfma16(a0l, bh, ax[0]);
      am[1] = mfma16(a1h, bh, am[1]);
      ax[1] = mfma16(a1h, bl, ax[1]);
      ax[1] = mfma16(a1l, bh, ax[1]);
    }
  }

  // deposit gates: warp wid holds gate wid for 16 j x 32 b
#pragma unroll
  for (int i2 = 0; i2 < 2; ++i2)
#pragma unroll
    for (int r = 0; r < 4; ++r)
      sGate[wid][i2 * 16 + l4 * 4 + r][ln] = am[i2][r] + ax[i2][r] * (1.0f / 2048.0f);
  __syncthreads();

  // cell update: thread owns (b, 2 consecutive j)
  {
    const int b = tid >> 3, cj = (tid & 7) * 2;
    const int j = jt * 16 + cj;
    float iv0 = sGate[0][b][cj] + bias[d * 2048 + j];
    float iv1 = sGate[0][b][cj + 1] + bias[d * 2048 + j + 1];
    float fv0 = sGate[1][b][cj] + bias[d * 2048 + 512 + j];
    float fv1 = sGate[1][b][cj + 1] + bias[d * 2048 + 512 + j + 1];
    float gv0 = sGate[2][b][cj] + bias[d * 2048 + 1024 + j];
    float gv1 = sGate[2][b][cj + 1] + bias[d * 2048 + 1024 + j + 1];
    float ov0 = sGate[3][b][cj] + bias[d * 2048 + 1536 + j];
    float ov1 = sGate[3][b][cj + 1] + bias[d * 2048 + 1536 + j + 1];
    long co = ((long)s * 32 + b) * 512 + j;
    float2 cold = *(const float2*)&cDec[co];
    float c0 = sigf(fv0) * cold.x + sigf(iv0) * tanhf(gv0);
    float c1 = sigf(fv1) * cold.y + sigf(iv1) * tanhf(gv1);
    *(float2*)&cDec[co] = make_float2(c0, c1);
    float h0 = sigf(ov0) * tanhf(c0);
    float h1 = sigf(ov1) * tanhf(c1);
    f16 h0h, h0l, h1h, h1l;
    split2(h0, &h0h, &h0l);
    split2(h1, &h1h, &h1l);
    unsigned phi = packh(h0h, h1h), plo = packh(h0l, h1l);
    *(unsigned*)&dhOutH[co] = phi;
    *(unsigned*)&dhOutL[co] = plo;
    long xo = (long)b * 1024 + d * 512 + j;
    *(unsigned*)&xoH[xo] = phi;
    *(unsigned*)&xoL[xo] = plo;
  }
}

// ---------------- fused decoder LSTM step (64 blocks; standalone dispatch) ---------
template <int XK, bool GATHER>
__global__ __launch_bounds__(256, 1) void k_dec(
    const int* __restrict__ tok, const float* __restrict__ emb,
    const f16* __restrict__ xH, const f16* __restrict__ xL,
    const f16* __restrict__ WihH, const f16* __restrict__ WihL,
    const f16* __restrict__ WhhH, const f16* __restrict__ WhhL,
    const float* __restrict__ bias,
    const f16* __restrict__ dhInH, const f16* __restrict__ dhInL,
    f16* __restrict__ dhOutH, f16* __restrict__ dhOutL,
    float* __restrict__ cDec, f16* __restrict__ xoH, f16* __restrict__ xoL,
    int layer) {
  __shared__ f16 sA[2][32][72];
  __shared__ f16 sB[2][64][72];
  __shared__ float sGate[4][32][17];
  dec_body<XK, GATHER>(blockIdx.x, tok, emb, xH, xL, WihH, WihL, WhhH, WhhL, bias,
                       dhInH, dhInL, dhOutH, dhOutL, cDec, xoH, xoL, layer, sA, sB,
                       sGate);
}

// ---------------- pred GEMM: C[32,50000] = x2[32,1024] @ predW^T + b ---------------
// v3: A staged in two K-halves (66 KB LDS -> 2 blocks/CU). B straight into MFMA
// register fragments, quad-buffered 3 slices deep; barrier-free inner loop.
__global__ __launch_bounds__(256, 2) void k_pred(
    const f16* __restrict__ xH, const f16* __restrict__ xL,    // [32][1024]
    const f16* __restrict__ BH, const f16* __restrict__ BL,    // [50000][1024]
    const float* __restrict__ bias, float* __restrict__ C) {   // [32][50000]
  __shared__ f16 sAh[32][520];
  __shared__ f16 sAl[32][520];
  const int tid = threadIdx.x;

  auto stageA = [&](int koff) {
#pragma unroll
    for (int q = 0; q < 8; ++q) {
      int idx = tid + q * 256;          // 2048 chunks of 8 f16
      int r = idx >> 6, c8 = idx & 63;  // row, 8-col chunk within half
      *(uint4*)&sAh[r][c8 * 8] = *(const uint4*)(xH + r * 1024 + koff + c8 * 8);
      *(uint4*)&sAl[r][c8 * 8] = *(const uint4*)(xL + r * 1024 + koff + c8 * 8);
    }
  };

  const int wid = tid >> 6, lane = tid & 63;
  const int ln = lane & 15, l4 = lane >> 4;
  const int n0 = blockIdx.x * 128 + wid * 32;

  const int row0 = n0 + ln, row1 = n0 + 16 + ln;
  const f16* pbh0 = BH + (long)(row0 < 50000 ? row0 : 0) * 1024 + l4 * 8;
  const f16* pbl0 = BL + (long)(row0 < 50000 ? row0 : 0) * 1024 + l4 * 8;
  const f16* pbh1 = BH + (long)(row1 < 50000 ? row1 : 0) * 1024 + l4 * 8;
  const f16* pbl1 = BL + (long)(row1 < 50000 ? row1 : 0) * 1024 + l4 * 8;

  f32x4 am[2][2], ax[2][2];
#pragma unroll
  for (int i = 0; i < 2; ++i)
#pragma unroll
    for (int j = 0; j < 2; ++j) {
      am[i][j] = (f32x4){0.f, 0.f, 0.f, 0.f};
      ax[i][j] = (f32x4){0.f, 0.f, 0.f, 0.f};
    }

  f16x8 b0[4], b1[4], b2[4], b3[4];
  auto loadB = [&](int s, f16x8* buf) {
    const long o = (long)s * 32;
    buf[0] = *(const f16x8*)(pbh0 + o);
    buf[1] = *(const f16x8*)(pbl0 + o);
    buf[2] = *(const f16x8*)(pbh1 + o);
    buf[3] = *(const f16x8*)(pbl1 + o);
  };
  auto comp = [&](int s, const f16x8* buf) {
    const int kc = (s & 15) * 32 + l4 * 8;  // LDS offset within current half
    f16x8 a0h = *(const f16x8*)&sAh[ln][kc];
    f16x8 a1h = *(const f16x8*)&sAh[16 + ln][kc];
    f16x8 a0l = *(const f16x8*)&sAl[ln][kc];
    f16x8 a1l = *(const f16x8*)&sAl[16 + ln][kc];
    am[0][0] = mfma16(a0h, buf[0], am[0][0]);
    ax[0][0] = mfma16(a0h, buf[1], ax[0][0]);
    ax[0][0] = mfma16(a0l, buf[0], ax[0][0]);
    am[1][0] = mfma16(a1h, buf[0], am[1][0]);
    ax[1][0] = mfma16(a1h, buf[1], ax[1][0]);
    ax[1][0] = mfma16(a1l, buf[0], ax[1][0]);
    am[0][1] = mfma16(a0h, buf[2], am[0][1]);
    ax[0][1] = mfma16(a0h, buf[3], ax[0][1]);
    ax[0][1] = mfma16(a0l, buf[2], ax[0][1]);
    am[1][1] = mfma16(a1h, buf[2], am[1][1]);
    ax[1][1] = mfma16(a1h, buf[3], ax[1][1]);
    ax[1][1] = mfma16(a1l, buf[2], ax[1][1]);
  };

  stageA(0);
  loadB(0, b0);
  loadB(1, b1);
  loadB(2, b2);
  __syncthreads();
#pragma unroll
  for (int h = 0; h < 2; ++h) {
    if (h) {
      __syncthreads();  // all warps done reading half 0
      stageA(512);
      __syncthreads();
    }
#pragma unroll 1
    for (int s = h * 16; s < h * 16 + 16; s += 4) {
      loadB(s + 3, b3);  // over-read past slice 31 stays inside ws planes: harmless
      comp(s, b0);
      loadB(s + 4, b0);
      comp(s + 1, b1);
      loadB(s + 5, b1);
      comp(s + 2, b2);
      loadB(s + 6, b2);
      comp(s + 3, b3);
    }
  }

#pragma unroll
  for (int j = 0; j < 2; ++j) {
    const int col = n0 + j * 16 + ln;
    if (col < 50000) {
      const float bv = bias[col];
#pragma unroll
      for (int i = 0; i < 2; ++i)
#pragma unroll
        for (int r = 0; r < 4; ++r) {
          const int row = i * 16 + l4 * 4 + r;
          C[(long)row * 50000 + col] = am[i][j][r] + ax[i][j][r] * (1.0f / 2048.0f) + bv;
        }
    }
  }
}

// ---------------- VAE elementwise (adds mu/lv biases) -------------------------------
__global__ void k_vae(const float* __restrict__ mlOut, const float* __restrict__ mub,
                      const float* __restrict__ lvb, const float* __restrict__ zn,
                      float* __restrict__ outMu, float* __restrict__ outLv,
                      float* __restrict__ outZ, f16* __restrict__ zHi,
                      f16* __restrict__ zLo) {
  int i = blockIdx.x * 256 + threadIdx.x;
  if (i >= 4 * 32 * 512) return;
  int bj = i & (32 * 512 - 1);
  int j = i & 511;
  float m = mlOut[i] + mub[j];
  float l = mlOut[65536 + i] + lvb[j];
  float z = zn[bj] * expf(0.5f * l) + m;
  outMu[i] = m;
  outLv[i] = l;
  outZ[i] = z;
  split2(z, &zHi[i], &zLo[i]);
}

// ---------------- decoder init ------------------------------------------------------
__global__ void k_decinit(const float* __restrict__ hInit, const float* __restrict__ cEnc,
                          const int* __restrict__ summary, f16* __restrict__ dhHi,
                          f16* __restrict__ dhLo, float* __restrict__ cDec,
                          int* __restrict__ tok) {
  int i = blockIdx.x * 256 + threadIdx.x;
  if (i < 4 * 32 * 512) {
    split2(hInit[i], &dhHi[i], &dhLo[i]);
    cDec[i] = cEnc[i];
  }
  if (i < 32) tok[i] = summary[i];  // summary[0][b]
}

// ---------------- fused log-softmax + argmax (one 1024-thread WG per batch row) ----
__global__ __launch_bounds__(1024) void k_lsm(const float* __restrict__ logits,
                                              float* __restrict__ outs,
                                              int* __restrict__ tok, int t) {
  const int b = blockIdx.x;
  const int tid = threadIdx.x;
  const float* lg = logits + (long)b * 50000;
  float m = -INFINITY, s = 0.0f;
  int am = 0;
  for (int v = tid; v < 50000; v += 1024) {
    float x = lg[v];
    if (x > m) {
      s = s * expf(m - x) + 1.0f;
      m = x;
      am = v;
    } else {
      s += expf(x - m);
    }
  }
  __shared__ float sm[1024], ss[1024];
  __shared__ int sa[1024];
  sm[tid] = m; ss[tid] = s; sa[tid] = am;
  __syncthreads();
  for (int o = 512; o > 0; o >>= 1) {
    if (tid < o) {
      float m2 = sm[tid + o], s2 = ss[tid + o];
      int a2 = sa[tid + o];
      float m1 = sm[tid], s1 = ss[tid];
      int a1 = sa[tid];
      if (m2 > m1 || (m2 == m1 && a2 < a1)) {
        sm[tid] = m2; ss[tid] = s2 + s1 * expf(m1 - m2); sa[tid] = a2;
      } else {
        ss[tid] = s1 + s2 * expf(m2 - m1);
      }
    }
    __syncthreads();
  }
  float lse = sm[0] + logf(ss[0]);
  float* ob = outs + ((long)t * 32 + b) * 50000;
  for (int v = tid; v < 50000; v += 1024) ob[v] = lg[v] - lse;
  if (tid == 0) tok[b] = sa[0];
}

// ====================================================================================
extern "C" void kernel_launch(void* const* d_in, const int* in_sizes, int n_in,
                              void* d_out, int out_size, void* d_ws, size_t ws_size,
                              hipStream_t stream) {
  const int* article = (const int*)d_in[0];
  const int* summary = (const int*)d_in[1];
  const float* z_noise = (const float*)d_in[2];
  const float* enc_emb = (const float*)d_in[3];
  const float* e0Wih = (const float*)d_in[4];
  const float* e0Whh = (const float*)d_in[5];
  const float* e0b = (const float*)d_in[6];
  const float* e1Wih = (const float*)d_in[7];
  const float* e1Whh = (const float*)d_in[8];
  const float* e1b = (const float*)d_in[9];
  const float* muW = (const float*)d_in[10];
  const float* mub = (const float*)d_in[11];
  const float* lvW = (const float*)d_in[12];
  const float* lvb = (const float*)d_in[13];
  const float* dhW = (const float*)d_in[14];
  const float* dhb = (const float*)d_in[15];
  const float* dec_emb = (const float*)d_in[16];
  const float* d0Wih = (const float*)d_in[17];
  const float* d0Whh = (const float*)d_in[18];
  const float* d0b = (const float*)d_in[19];
  const float* d1Wih = (const float*)d_in[20];
  const float* d1Whh = (const float*)d_in[21];
  const float* d1b = (const float*)d_in[22];
  const float* predW = (const float*)d_in[23];
  const float* predb = (const float*)d_in[24];
  float* out = (float*)d_out;
  (void)in_sizes; (void)n_in; (void)out_size; (void)ws_size;

  char* w = (char*)d_ws;
  size_t off = 0;
  auto alloc = [&](size_t bytes) -> void* {
    void* p = w + off;
    off += (bytes + 255) & ~(size_t)255;
    return p;
  };

  f16* e0WihH = (f16*)alloc(4096L * 320 * 2);
  f16* e0WihL = (f16*)alloc(4096L * 320 * 2);
  f16* e0WhhH = (f16*)alloc(4096L * 512 * 2);
  f16* e0WhhL = (f16*)alloc(4096L * 512 * 2);
  f16* e1WihH = (f16*)alloc(4096L * 1024 * 2);
  f16* e1WihL = (f16*)alloc(4096L * 1024 * 2);
  f16* e1WhhH = (f16*)alloc(4096L * 512 * 2);
  f16* e1WhhL = (f16*)alloc(4096L * 512 * 2);
  f16* d0WihH = (f16*)alloc(4096L * 320 * 2);
  f16* d0WihL = (f16*)alloc(4096L * 320 * 2);
  f16* d0WhhH = (f16*)alloc(4096L * 512 * 2);
  f16* d0WhhL = (f16*)alloc(4096L * 512 * 2);
  f16* d1WihH = (f16*)alloc(4096L * 1024 * 2);
  f16* d1WihL = (f16*)alloc(4096L * 1024 * 2);
  f16* d1WhhH = (f16*)alloc(4096L * 512 * 2);
  f16* d1WhhL = (f16*)alloc(4096L * 512 * 2);
  f16* mlWH = (f16*)alloc(2L * 262144 * 2);   // muW hi | lvW hi
  f16* mlWL = (f16*)alloc(2L * 262144 * 2);
  f16* dhWH = (f16*)alloc(512L * 512 * 2);
  f16* dhWL = (f16*)alloc(512L * 512 * 2);
  f16* predH = (f16*)alloc(50000L * 1024 * 2);
  f16* predL = (f16*)alloc(50000L * 1024 * 2);
  f16* embH = (f16*)alloc(12800L * 320 * 2);
  f16* embL = (f16*)alloc(12800L * 320 * 2);
  f16* o0H = (f16*)alloc(12800L * 1024 * 2);
  f16* o0L = (f16*)alloc(12800L * 1024 * 2);
  float* Gx = (float*)alloc(12800L * 4096 * 4);
  f16* hEncH = (f16*)alloc(2L * 2 * 32 * 512 * 2);
  f16* hEncL = (f16*)alloc(2L * 2 * 32 * 512 * 2);
  float* hid = (float*)alloc(128L * 512 * 4);
  float* cEnc = (float*)alloc(128L * 512 * 4);
  f16* hidH = (f16*)alloc(128L * 512 * 2);
  f16* hidL = (f16*)alloc(128L * 512 * 2);
  float* mlOut = (float*)alloc(2L * 65536 * 4);  // mu | lv (pre-bias)
  f16* zH = (f16*)alloc(128L * 512 * 2);
  f16* zL = (f16*)alloc(128L * 512 * 2);
  float* hInit = (float*)alloc(128L * 512 * 4);
  f16* dhH = (f16*)alloc(2L * 65536 * 2);  // [2 par][4][32][512]
  f16* dhL = (f16*)alloc(2L * 65536 * 2);
  float* cDec = (float*)alloc(4L * 32 * 512 * 4);
  f16* x1H = (f16*)alloc(32L * 1024 * 2);
  f16* x1L = (f16*)alloc(32L * 1024 * 2);
  f16* x2H = (f16*)alloc(32L * 1024 * 2);
  f16* x2L = (f16*)alloc(32L * 1024 * 2);
  float* logits = (float*)alloc(32L * 50000 * 4);
  int* tok = (int*)alloc(256);
  unsigned* bar = (unsigned*)alloc(2048);  // 512 words of flags

  // ---- single prep kernel: all splits + enc gather + bar reset ----
  SegTab tab;
  long cum = 0;
  int si = 0;
  auto seg = [&](const float* src, const int* idx, f16* hi, f16* lo, long rows, int cs,
                 int cd) {
    cum += rows * cd;
    tab.s[si++] = Seg{src, idx, hi, lo, cum, cs, cd};
  };
  seg(e0Wih, nullptr, e0WihH, e0WihL, 4096, 300, 320);
  seg(e0Whh, nullptr, e0WhhH, e0WhhL, 4096, 512, 512);
  seg(e1Wih, nullptr, e1WihH, e1WihL, 4096, 1024, 1024);
  seg(e1Whh, nullptr, e1WhhH, e1WhhL, 4096, 512, 512);
  seg(d0Wih, nullptr, d0WihH, d0WihL, 4096, 300, 320);
  seg(d0Whh, nullptr, d0WhhH, d0WhhL, 4096, 512, 512);
  seg(d1Wih, nullptr, d1WihH, d1WihL, 4096, 1024, 1024);
  seg(d1Whh, nullptr, d1WhhH, d1WhhL, 4096, 512, 512);
  seg(muW, nullptr, mlWH, mlWL, 512, 512, 512);
  seg(lvW, nullptr, mlWH + 262144, mlWL + 262144, 512, 512, 512);
  seg(dhW, nullptr, dhWH, dhWL, 512, 512, 512);
  seg(predW, nullptr, predH, predL, 50000, 1024, 1024);
  seg(enc_emb, article, embH, embL, 12800, 300, 320);
  k_prep<<<8192, 256, 0, stream>>>(tab, cum, bar);

  // ---- encoder ----
  k_gemm<128><<<dim3(32, 100, 1), 256, 0, stream>>>(embH, embL, e0WihH, e0WihL, e0b, Gx,
                                                    12800, 4096, 320, 0, 0, 0);
  k_lstm<<<64, 256, 0, stream>>>(e0WhhH, e0WhhL, Gx, hEncH, hEncL, o0H, o0L, hid, hidH,
                                 hidL, cEnc, bar, 400, 0);
  k_gemm<128><<<dim3(32, 100, 1), 256, 0, stream>>>(o0H, o0L, e1WihH, e1WihL, e1b, Gx,
                                                    12800, 4096, 1024, 0, 0, 0);
  k_lstm<<<64, 256, 0, stream>>>(e1WhhH, e1WhhL, Gx, hEncH, hEncL, (f16*)nullptr,
                                 (f16*)nullptr, hid, hidH, hidL, cEnc, bar + 128, 400, 1);

  // ---- VAE (mu+lv batched) ----
  k_gemm<32><<<dim3(4, 4, 2), 256, 0, stream>>>(hidH, hidL, mlWH, mlWL,
                                                (const float*)nullptr, mlOut, 128, 512,
                                                512, 0, 262144, 65536);
  k_vae<<<256, 256, 0, stream>>>(mlOut, mub, lvb, z_noise, out + 24000000L,
                                 out + 24065536L, out + 24131072L, zH, zL);
  k_gemm<32><<<dim3(4, 4, 1), 256, 0, stream>>>(zH, zL, dhWH, dhWL, dhb, hInit, 128, 512,
                                                512, 0, 0, 0);
  k_decinit<<<256, 256, 0, stream>>>(hInit, cEnc, summary, dhH, dhL, cDec, tok);

  // ---- decoder greedy loop (4 nodes/step) ----
  for (int t = 0; t < 15; ++t) {
    int par = t & 1;
    f16* dIH = dhH + (long)par * 65536;
    f16* dIL = dhL + (long)par * 65536;
    f16* dOH = dhH + (long)(par ^ 1) * 65536;
    f16* dOL = dhL + (long)(par ^ 1) * 65536;
    k_dec<320, true><<<64, 256, 0, stream>>>(tok, dec_emb, (const f16*)nullptr,
                                             (const f16*)nullptr, d0WihH, d0WihL, d0WhhH,
                                             d0WhhL, d0b, dIH, dIL, dOH, dOL, cDec, x1H,
                                             x1L, 0);
    k_dec<1024, false><<<64, 256, 0, stream>>>((const int*)nullptr, (const float*)nullptr,
                                               x1H, x1L, d1WihH, d1WihL, d1WhhH, d1WhhL,
                                               d1b, dIH, dIL, dOH, dOL, cDec, x2H, x2L,
                                               1);
    k_pred<<<391, 256, 0, stream>>>(x2H, x2L, predH, predL, predb, logits);
    k_lsm<<<32, 1024, 0, stream>>>(logits, out, tok, t);
  }
}